// Round 1
// baseline (2067.348 us; speedup 1.0000x reference)
//
#include <hip/hip_runtime.h>
#include <hip/hip_bf16.h>

typedef unsigned short ushort_t;
typedef short short8 __attribute__((ext_vector_type(8)));
typedef float floatx4 __attribute__((ext_vector_type(4)));

#define NB 65536
#define TB 8

// ws layout (bytes):
//   [0, 770048)                 : transposed f32 weights (192512 floats)
//       +0      WcT   [128][128]
//       +16384  WmT   [256][128]
//       +49152  WdT   [64][128]
//       +57344  WpT   [32][128]
//       +61440  WrT   [512][128]
//       +126976 inwT  [128][384]
//       +176128 outwT [128][128]
//   [770048, 2080768)           : fus_w bf16 padded [1024][640]
//   [2080768, 2080768+83886080) : y bf16 [65536][640]

__device__ __forceinline__ ushort_t f2bf(float f) {
  __hip_bfloat16 h = __float2bfloat16(f);
  ushort_t u;
  __builtin_memcpy(&u, &h, 2);
  return u;
}
__device__ __forceinline__ float bf2f(ushort_t u) {
  unsigned int x = ((unsigned int)u) << 16;
  return __uint_as_float(x);
}

// ---------------- K0: weight prep ----------------
__global__ __launch_bounds__(256) void k0_prep(
    const float* __restrict__ Wc, const float* __restrict__ Wm,
    const float* __restrict__ Wd, const float* __restrict__ Wp,
    const float* __restrict__ Wr, const float* __restrict__ in_w,
    const float* __restrict__ out_w, const float* __restrict__ fus_w,
    float* __restrict__ wsf, ushort_t* __restrict__ fwb) {
  int g = blockIdx.x * 256 + threadIdx.x;
  if (g < 192512) {
    int local, O, I;
    const float* src;
    float* dst;
    if (g < 16384)       { local = g;          src = Wc;    dst = wsf;          O = 128; I = 128; }
    else if (g < 49152)  { local = g - 16384;  src = Wm;    dst = wsf + 16384;  O = 128; I = 256; }
    else if (g < 57344)  { local = g - 49152;  src = Wd;    dst = wsf + 49152;  O = 128; I = 64;  }
    else if (g < 61440)  { local = g - 57344;  src = Wp;    dst = wsf + 57344;  O = 128; I = 32;  }
    else if (g < 126976) { local = g - 61440;  src = Wr;    dst = wsf + 61440;  O = 128; I = 512; }
    else if (g < 176128) { local = g - 126976; src = in_w;  dst = wsf + 126976; O = 384; I = 128; }
    else                 { local = g - 176128; src = out_w; dst = wsf + 176128; O = 128; I = 128; }
    int o = local / I, i = local - o * I;
    dst[i * O + o] = src[local];  // W[O][I] -> WT[I][O]
  }
  if (g < 1024 * 640) {
    int n = g / 640;
    float v = (n < 992) ? fus_w[g] : 0.0f;
    fwb[g] = f2bf(v);
  }
}

// ---------------- K1 helpers ----------------
template <int KM>
__device__ __forceinline__ void load_emb(const float* __restrict__ src,
                                         float (*s_emb)[992], int off, long r0,
                                         int t) {
  constexpr int C4 = KM / 4;
  constexpr int N4 = TB * C4;
  for (int i = t; i < N4; i += 256) {
    int r = i / C4;
    int c4 = i - r * C4;
    float4 v = *(const float4*)(src + (r0 + r) * KM + c4 * 4);
    *(float4*)&s_emb[r][off + c4 * 4] = v;
  }
}

template <int KM>
__device__ __forceinline__ void proj_mod(const float (*s_emb)[992],
                                         float* __restrict__ s_x,
                                         const float* __restrict__ Wt,  // [KM][128]
                                         const float* __restrict__ bias_p,
                                         int off, int mod, int t) {
  int c = t & 127, rq = t >> 7;
  float a0 = 0.f, a1 = 0.f, a2 = 0.f, a3 = 0.f;
  for (int k = 0; k < KM; k += 4) {
    float w0 = Wt[(k + 0) * 128 + c];
    float w1 = Wt[(k + 1) * 128 + c];
    float w2 = Wt[(k + 2) * 128 + c];
    float w3 = Wt[(k + 3) * 128 + c];
    float4 e0 = *(const float4*)&s_emb[rq * 4 + 0][off + k];
    float4 e1 = *(const float4*)&s_emb[rq * 4 + 1][off + k];
    float4 e2 = *(const float4*)&s_emb[rq * 4 + 2][off + k];
    float4 e3 = *(const float4*)&s_emb[rq * 4 + 3][off + k];
    a0 += e0.x * w0 + e0.y * w1 + e0.z * w2 + e0.w * w3;
    a1 += e1.x * w0 + e1.y * w1 + e1.z * w2 + e1.w * w3;
    a2 += e2.x * w0 + e2.y * w1 + e2.z * w2 + e2.w * w3;
    a3 += e3.x * w0 + e3.y * w1 + e3.z * w2 + e3.w * w3;
  }
  float b = bias_p[c];
  s_x[((rq * 4 + 0) * 5 + mod) * 128 + c] = a0 + b;
  s_x[((rq * 4 + 1) * 5 + mod) * 128 + c] = a1 + b;
  s_x[((rq * 4 + 2) * 5 + mod) * 128 + c] = a2 + b;
  s_x[((rq * 4 + 3) * 5 + mod) * 128 + c] = a3 + b;
}

// ---------------- K1: fused projections + MHA + LN -> y bf16 ----------------
__global__ __launch_bounds__(256) void k1_fused(
    const float* __restrict__ cat, const float* __restrict__ menu,
    const float* __restrict__ din, const float* __restrict__ pri,
    const float* __restrict__ rev, const float* __restrict__ wsf,
    const float* __restrict__ bc, const float* __restrict__ bm,
    const float* __restrict__ bd, const float* __restrict__ bp,
    const float* __restrict__ br, const float* __restrict__ in_b,
    const float* __restrict__ out_b, const float* __restrict__ ln_g,
    const float* __restrict__ ln_b, ushort_t* __restrict__ Y) {
  __shared__ float s_emb[TB][992];   // 31744 B; later aliased as qkv bf16 [40][384]
  __shared__ float s_x[TB * 640];    // 20480 B, token-flat: x[tok*128 + c], tok=r*5+m
  __shared__ float s_att[TB * 4 * 25];  // 3200 B: [(r*4+h)*25 + m*5 + n]
  ushort_t* s_qkv = (ushort_t*)s_emb;

  const int t = threadIdx.x;
  const long r0 = (long)blockIdx.x * TB;

  // S0: stage embeddings, f32, concatenated per row
  load_emb<128>(cat, s_emb, 0, r0, t);
  load_emb<256>(menu, s_emb, 128, r0, t);
  load_emb<64>(din, s_emb, 384, r0, t);
  load_emb<32>(pri, s_emb, 448, r0, t);
  load_emb<512>(rev, s_emb, 480, r0, t);
  __syncthreads();

  // S1: modality projections -> s_x (f32)
  proj_mod<128>(s_emb, s_x, wsf + 0,     bc, 0,   0, t);
  proj_mod<256>(s_emb, s_x, wsf + 16384, bm, 128, 1, t);
  proj_mod<64> (s_emb, s_x, wsf + 49152, bd, 384, 2, t);
  proj_mod<32> (s_emb, s_x, wsf + 57344, bp, 448, 3, t);
  proj_mod<512>(s_emb, s_x, wsf + 61440, br, 480, 4, t);
  __syncthreads();  // emb dead; s_qkv may overwrite it

  // S2: qkv = x @ in_w^T + in_b, stored bf16 in the dead emb buffer
  {
    const float* iwT = wsf + 126976;  // [128][384]
    int ct = t & 63, tt = t >> 6;     // toks tt*10 .. tt*10+9
    for (int cb = 0; cb < 6; ++cb) {
      int col = cb * 64 + ct;
      float acc[10];
#pragma unroll
      for (int j = 0; j < 10; ++j) acc[j] = 0.f;
      for (int k = 0; k < 128; k += 4) {
        float w0 = iwT[(k + 0) * 384 + col];
        float w1 = iwT[(k + 1) * 384 + col];
        float w2 = iwT[(k + 2) * 384 + col];
        float w3 = iwT[(k + 3) * 384 + col];
#pragma unroll
        for (int j = 0; j < 10; ++j) {
          float4 xv = *(const float4*)&s_x[(tt * 10 + j) * 128 + k];
          acc[j] += xv.x * w0 + xv.y * w1 + xv.z * w2 + xv.w * w3;
        }
      }
      float bias = in_b[col];
#pragma unroll
      for (int j = 0; j < 10; ++j)
        s_qkv[(tt * 10 + j) * 384 + col] = f2bf(acc[j] + bias);
    }
  }
  __syncthreads();

  // S3: scores = q.k / sqrt(32)
  for (int idx = t; idx < TB * 4 * 25; idx += 256) {
    int n = idx % 5;
    int tmp = idx / 5;
    int m = tmp % 5;
    int tmp2 = tmp / 5;  // r*4 + h
    int h = tmp2 & 3;
    int r = tmp2 >> 2;
    const ushort_t* qp = s_qkv + (r * 5 + m) * 384 + h * 32;
    const ushort_t* kp = s_qkv + (r * 5 + n) * 384 + 128 + h * 32;
    float s = 0.f;
#pragma unroll
    for (int i = 0; i < 32; i += 2) {
      unsigned int uq = *(const unsigned int*)(qp + i);
      unsigned int uk = *(const unsigned int*)(kp + i);
      s += __uint_as_float(uq << 16) * __uint_as_float(uk << 16);
      s += __uint_as_float(uq & 0xffff0000u) * __uint_as_float(uk & 0xffff0000u);
    }
    s_att[tmp2 * 25 + m * 5 + n] = s * 0.17677669529663689f;
  }
  __syncthreads();

  // S3b: softmax over n (5)
  if (t < TB * 4 * 5) {
    int m = t % 5;
    int rh = t / 5;
    float* row = s_att + rh * 25 + m * 5;
    float s0 = row[0], s1 = row[1], s2 = row[2], s3 = row[3], s4 = row[4];
    float mx = fmaxf(fmaxf(fmaxf(s0, s1), fmaxf(s2, s3)), s4);
    float e0 = __expf(s0 - mx), e1 = __expf(s1 - mx), e2 = __expf(s2 - mx);
    float e3 = __expf(s3 - mx), e4 = __expf(s4 - mx);
    float inv = 1.f / (e0 + e1 + e2 + e3 + e4);
    row[0] = e0 * inv; row[1] = e1 * inv; row[2] = e2 * inv;
    row[3] = e3 * inv; row[4] = e4 * inv;
  }
  __syncthreads();

  // S4: ctx = attn @ v -> f32 into the dead q+k slots (128 floats per token)
  for (int rep = 0; rep < TB * 640 / 256; ++rep) {
    int oi = rep * 256 + t;
    int cc = oi & 127;
    int tm = oi >> 7;  // token 0..39
    int r = tm / 5, m = tm - r * 5;
    int h = cc >> 5;
    const float* aw = s_att + (r * 4 + h) * 25 + m * 5;
    float s = 0.f;
#pragma unroll
    for (int n = 0; n < 5; ++n)
      s += aw[n] * bf2f(s_qkv[(r * 5 + n) * 384 + 256 + cc]);
    float* ctx = (float*)(s_qkv + tm * 384);
    ctx[cc] = s;
  }
  __syncthreads();

  // S5: out-proj + residual + LayerNorm, write y bf16
  {
    const float* owT = wsf + 176128;  // [128][128]
    int w = t >> 6, l = t & 63;
    int c0 = l, c1 = l + 64;
    float acc0[10], acc1[10];
#pragma unroll
    for (int j = 0; j < 10; ++j) { acc0[j] = 0.f; acc1[j] = 0.f; }
    for (int k = 0; k < 128; k += 4) {
      float w00 = owT[(k + 0) * 128 + c0], w01 = owT[(k + 0) * 128 + c1];
      float w10 = owT[(k + 1) * 128 + c0], w11 = owT[(k + 1) * 128 + c1];
      float w20 = owT[(k + 2) * 128 + c0], w21 = owT[(k + 2) * 128 + c1];
      float w30 = owT[(k + 3) * 128 + c0], w31 = owT[(k + 3) * 128 + c1];
#pragma unroll
      for (int j = 0; j < 10; ++j) {
        int tok = w * 10 + j;
        const float* ctx = (const float*)(s_qkv + tok * 384);
        float4 cv = *(const float4*)&ctx[k];
        acc0[j] += cv.x * w00 + cv.y * w10 + cv.z * w20 + cv.w * w30;
        acc1[j] += cv.x * w01 + cv.y * w11 + cv.z * w21 + cv.w * w31;
      }
    }
    float ob0 = out_b[c0], ob1 = out_b[c1];
    float g0 = ln_g[c0], g1 = ln_g[c1];
    float be0 = ln_b[c0], be1 = ln_b[c1];
    for (int j = 0; j < 10; ++j) {
      int tok = w * 10 + j;
      float y0 = acc0[j] + ob0 + s_x[tok * 128 + c0];
      float y1 = acc1[j] + ob1 + s_x[tok * 128 + c1];
      float sum = y0 + y1;
#pragma unroll
      for (int d = 1; d < 64; d <<= 1) sum += __shfl_xor(sum, d, 64);
      float mu = sum * (1.0f / 128.0f);
      float d0 = y0 - mu, d1 = y1 - mu;
      float vv = d0 * d0 + d1 * d1;
#pragma unroll
      for (int d = 1; d < 64; d <<= 1) vv += __shfl_xor(vv, d, 64);
      float rs = rsqrtf(vv * (1.0f / 128.0f) + 1e-5f);
      long base = (r0 * 5 + tok) * 128;
      Y[base + c0] = f2bf(d0 * rs * g0 + be0);
      Y[base + c1] = f2bf(d1 * rs * g1 + be1);
    }
  }
}

// ---------------- K2: fusion GEMM, bf16 MFMA, out = y @ fus_w^T + fus_b ----
// C[M=65536][992] f32, A=y bf16 [M][640], Bt=fus_w bf16 padded [1024][640]
__global__ __launch_bounds__(256) void k2_gemm(const ushort_t* __restrict__ A,
                                               const ushort_t* __restrict__ Bt,
                                               const float* __restrict__ bias,
                                               float* __restrict__ C) {
  constexpr int K = 640, NOUT = 992;
  __shared__ ushort_t As[128 * 32];
  __shared__ ushort_t Bs[128 * 32];
  const int m0 = blockIdx.y * 128;
  const int n0 = blockIdx.x * 128;
  const int t = threadIdx.x;
  const int w = t >> 6, l = t & 63;
  const int wm = (w & 1) * 64, wn = (w >> 1) * 64;
  const int quad = l >> 4, lr = l & 15;

  floatx4 acc[4][4] = {};

  for (int k0 = 0; k0 < K; k0 += 32) {
    __syncthreads();
#pragma unroll
    for (int i = 0; i < 2; ++i) {
      int flat = i * 256 + t;  // 512 x 16B chunks per tile
      int row = flat >> 2, seg = flat & 3;
      *(int4*)&As[row * 32 + seg * 8] =
          *(const int4*)&A[(long)(m0 + row) * K + k0 + seg * 8];
      *(int4*)&Bs[row * 32 + seg * 8] =
          *(const int4*)&Bt[(long)(n0 + row) * K + k0 + seg * 8];
    }
    __syncthreads();
    short8 af[4], bf[4];
#pragma unroll
    for (int mt = 0; mt < 4; ++mt)
      af[mt] = *(const short8*)&As[(wm + mt * 16 + lr) * 32 + quad * 8];
#pragma unroll
    for (int nt = 0; nt < 4; ++nt)
      bf[nt] = *(const short8*)&Bs[(wn + nt * 16 + lr) * 32 + quad * 8];
#pragma unroll
    for (int mt = 0; mt < 4; ++mt)
#pragma unroll
      for (int nt = 0; nt < 4; ++nt)
        acc[mt][nt] = __builtin_amdgcn_mfma_f32_16x16x32_bf16(
            af[mt], bf[nt], acc[mt][nt], 0, 0, 0);
  }

#pragma unroll
  for (int mt = 0; mt < 4; ++mt)
#pragma unroll
    for (int nt = 0; nt < 4; ++nt)
#pragma unroll
      for (int i = 0; i < 4; ++i) {
        int row = m0 + wm + mt * 16 + quad * 4 + i;
        int col = n0 + wn + nt * 16 + lr;
        if (col < NOUT)
          C[(long)row * NOUT + col] = acc[mt][nt][i] + bias[col];
      }
}

// ---------------- launch ----------------
extern "C" void kernel_launch(void* const* d_in, const int* in_sizes, int n_in,
                              void* d_out, int out_size, void* d_ws,
                              size_t ws_size, hipStream_t stream) {
  const float* cat   = (const float*)d_in[0];
  const float* menu  = (const float*)d_in[1];
  const float* din   = (const float*)d_in[2];
  const float* pri   = (const float*)d_in[3];
  const float* rev   = (const float*)d_in[4];
  const float* Wc    = (const float*)d_in[5];
  const float* bc    = (const float*)d_in[6];
  const float* Wm    = (const float*)d_in[7];
  const float* bm    = (const float*)d_in[8];
  const float* Wd    = (const float*)d_in[9];
  const float* bd    = (const float*)d_in[10];
  const float* Wp    = (const float*)d_in[11];
  const float* bp    = (const float*)d_in[12];
  const float* Wr    = (const float*)d_in[13];
  const float* br    = (const float*)d_in[14];
  const float* in_w  = (const float*)d_in[15];
  const float* in_b  = (const float*)d_in[16];
  const float* out_w = (const float*)d_in[17];
  const float* out_b = (const float*)d_in[18];
  const float* ln_g  = (const float*)d_in[19];
  const float* ln_b  = (const float*)d_in[20];
  const float* fus_w = (const float*)d_in[21];
  const float* fus_b = (const float*)d_in[22];

  float* wsf = (float*)d_ws;
  ushort_t* fwb = (ushort_t*)((char*)d_ws + 770048);
  ushort_t* Y = (ushort_t*)((char*)d_ws + 770048 + 1310720);
  float* out = (float*)d_out;

  k0_prep<<<2560, 256, 0, stream>>>(Wc, Wm, Wd, Wp, Wr, in_w, out_w, fus_w,
                                    wsf, fwb);
  k1_fused<<<NB / TB, 256, 0, stream>>>(cat, menu, din, pri, rev, wsf, bc, bm,
                                        bd, bp, br, in_b, out_b, ln_g, ln_b, Y);
  dim3 g2(8, NB / 128);
  k2_gemm<<<g2, 256, 0, stream>>>(Y, fwb, fus_b, out);
}